// Round 1
// baseline (612.262 us; speedup 1.0000x reference)
//
#include <hip/hip_runtime.h>
#include <hip/hip_bf16.h>
#include <math.h>

// Problem shape (fixed): B=4, S=1024, D=768, A=192, H=3, hd=64
#define BDIM 4
#define SDIM 1024
#define DDIM 768
#define ADIM 192
#define HDIM 3
#define HD   64
#define MROWS (BDIM*SDIM)      // 4096
#define NCHUNK (SDIM/32)       // 32
#define EPSLN 1e-6f

// ---------------- DPP wave reduction (64-lane sum, result broadcast) -------
template<int CTRL, int RMASK, bool BC>
__device__ __forceinline__ float dpp_add_step(float x) {
    int t = __builtin_amdgcn_update_dpp(0, __float_as_int(x), CTRL, RMASK, 0xf, BC);
    return x + __int_as_float(t);
}
__device__ __forceinline__ float wave_bcast_sum(float x) {
    x = dpp_add_step<0x111, 0xf, true >(x);
    x = dpp_add_step<0x112, 0xf, true >(x);
    x = dpp_add_step<0x114, 0xf, true >(x);
    x = dpp_add_step<0x118, 0xf, true >(x);
    x = dpp_add_step<0x142, 0xa, false>(x);
    x = dpp_add_step<0x143, 0xc, false>(x);
    return __int_as_float(__builtin_amdgcn_readlane(__float_as_int(x), 63));
}
__device__ __forceinline__ float rl(float v, int lane) {
    return __int_as_float(__builtin_amdgcn_readlane(__float_as_int(v), lane));
}
__device__ __forceinline__ float fast_rsq(float x) {
    float r;
    asm("v_rsq_f32 %0, %1" : "=v"(r) : "v"(x));
    return r;
}
// 5 simultaneous 64-lane sums via fused DPP adds (validated r7-r10).
__device__ __forceinline__ void red5_asm(float& a, float& b, float& c,
                                         float& d, float& e) {
#define R5_SHR(N)                                                              \
    asm("v_add_f32 %0, %0, %0 row_shr:" #N " row_mask:0xf bank_mask:0xf bound_ctrl:0" : "+v"(a)); \
    asm("v_add_f32 %0, %0, %0 row_shr:" #N " row_mask:0xf bank_mask:0xf bound_ctrl:0" : "+v"(b)); \
    asm("v_add_f32 %0, %0, %0 row_shr:" #N " row_mask:0xf bank_mask:0xf bound_ctrl:0" : "+v"(c)); \
    asm("v_add_f32 %0, %0, %0 row_shr:" #N " row_mask:0xf bank_mask:0xf bound_ctrl:0" : "+v"(d)); \
    asm("v_add_f32 %0, %0, %0 row_shr:" #N " row_mask:0xf bank_mask:0xf bound_ctrl:0" : "+v"(e));
#define R5_BC(N, RM)                                                           \
    asm("v_add_f32 %0, %0, %0 row_bcast:" #N " row_mask:" #RM " bank_mask:0xf" : "+v"(a)); \
    asm("v_add_f32 %0, %0, %0 row_bcast:" #N " row_mask:" #RM " bank_mask:0xf" : "+v"(b)); \
    asm("v_add_f32 %0, %0, %0 row_bcast:" #N " row_mask:" #RM " bank_mask:0xf" : "+v"(c)); \
    asm("v_add_f32 %0, %0, %0 row_bcast:" #N " row_mask:" #RM " bank_mask:0xf" : "+v"(d)); \
    asm("v_add_f32 %0, %0, %0 row_bcast:" #N " row_mask:" #RM " bank_mask:0xf" : "+v"(e));
    R5_SHR(1) R5_SHR(2) R5_SHR(4) R5_SHR(8)
    R5_BC(15, 0xa) R5_BC(31, 0xc)
#undef R5_SHR
#undef R5_BC
}

// ---------------- per-row LayerNorm stats: (mu, rstd) over 192 -------------
__global__ __launch_bounds__(64) void lnstats(
    const float* __restrict__ in, float2* __restrict__ st)
{
    int row = blockIdx.x, tid = threadIdx.x;
    float x0 = in[(size_t)row * ADIM + tid];
    float x1 = in[(size_t)row * ADIM + 64 + tid];
    float x2 = in[(size_t)row * ADIM + 128 + tid];
    float s1 = wave_bcast_sum((x0 + x1) + x2);
    float s2 = wave_bcast_sum(fmaf(x0, x0, fmaf(x1, x1, x2 * x2)));
    if (tid == 0) {
        float mu = s1 * (1.f / 192.f);
        float var = s2 * (1.f / 192.f) - mu * mu;
        st[row] = make_float2(mu, rsqrtf(var + EPSLN));
    }
}

// ---------------- Generic fp32 tiled GEMM: C = act(lnA(A)@B + bias) --------
template<int ACT, int LAYOUT, int LNA>
__global__ __launch_bounds__(256) void gemm_k(
    const float* __restrict__ A, const float* __restrict__ Bm,
    const float* __restrict__ bias, float* __restrict__ C,
    int M, int N, int K,
    const float2* __restrict__ lnst, const float* __restrict__ lng,
    const float* __restrict__ lnbb)
{
    __shared__ float As[16][68];
    __shared__ float Bs[16][68];
    const int tid = threadIdx.x;
    const int bm = blockIdx.y * 64, bn = blockIdx.x * 64;
    const int tr = tid >> 4, tc = tid & 15;
    float acc[4][4] = {};

    for (int k0 = 0; k0 < K; k0 += 16) {
        #pragma unroll
        for (int p = 0; p < 4; ++p) {
            int m = (tid >> 4) + p * 16;
            int kk = tid & 15;
            float av = A[(size_t)(bm + m) * K + k0 + kk];
            if (LNA) {
                float2 stv = lnst[bm + m];
                av = fmaf((av - stv.x) * stv.y, lng[k0 + kk], lnbb[k0 + kk]);
            }
            As[kk][m] = av;
        }
        #pragma unroll
        for (int p = 0; p < 4; ++p) {
            int kk = (tid >> 6) + p * 4;
            int n = tid & 63;
            Bs[kk][n] = Bm[(size_t)(k0 + kk) * N + bn + n];
        }
        __syncthreads();
        #pragma unroll
        for (int kk = 0; kk < 16; ++kk) {
            // 16B-aligned: As row stride 272B, offsets are multiples of 16B
            const float4 a4 = *(const float4*)&As[kk][tr * 4];
            const float4 b4 = *(const float4*)&Bs[kk][tc * 4];
            float aa[4] = {a4.x, a4.y, a4.z, a4.w};
            float bb[4] = {b4.x, b4.y, b4.z, b4.w};
            #pragma unroll
            for (int i = 0; i < 4; ++i)
                #pragma unroll
                for (int j = 0; j < 4; ++j)
                    acc[i][j] = fmaf(aa[i], bb[j], acc[i][j]);
        }
        __syncthreads();
    }

    #pragma unroll
    for (int i = 0; i < 4; ++i) {
        int m = bm + tr * 4 + i;
        #pragma unroll
        for (int j = 0; j < 4; ++j) {
            int n = bn + tc * 4 + j;
            float v = acc[i][j];
            if (bias) v += bias[n];
            if (ACT == 1) v = v / (1.f + __expf(-v));   // silu
            if (LAYOUT == 0) {
                C[(size_t)m * N + n] = v;
            } else {
                int b  = m >> 10, s = m & 1023;
                int hh = n >> 6,  d = n & 63;
                C[(((size_t)b * HDIM + hh) * SDIM + s) * HD + d] = v;
            }
        }
    }
}

// ---------------- fused QKV GEMM: one launch, blockIdx.z picks the head ----
__global__ __launch_bounds__(256) void gemm_qkv(
    const float* __restrict__ A, const float* __restrict__ BWq,
    const float* __restrict__ BWk, const float* __restrict__ BWv,
    float* __restrict__ Cbase)
{
    const float* Bm = (blockIdx.z == 0) ? BWq : (blockIdx.z == 1) ? BWk : BWv;
    float* C = Cbase + (size_t)blockIdx.z * ((size_t)MROWS * ADIM);
    __shared__ float As[16][68];
    __shared__ float Bs[16][68];
    const int tid = threadIdx.x;
    const int bm = blockIdx.y * 64, bn = blockIdx.x * 64;
    const int tr = tid >> 4, tc = tid & 15;
    float acc[4][4] = {};

    for (int k0 = 0; k0 < ADIM; k0 += 16) {
        #pragma unroll
        for (int p = 0; p < 4; ++p) {
            int m = (tid >> 4) + p * 16;
            int kk = tid & 15;
            As[kk][m] = A[(size_t)(bm + m) * ADIM + k0 + kk];
        }
        #pragma unroll
        for (int p = 0; p < 4; ++p) {
            int kk = (tid >> 6) + p * 4;
            int n = tid & 63;
            Bs[kk][n] = Bm[(size_t)(k0 + kk) * ADIM + bn + n];
        }
        __syncthreads();
        #pragma unroll
        for (int kk = 0; kk < 16; ++kk) {
            const float4 a4 = *(const float4*)&As[kk][tr * 4];
            const float4 b4 = *(const float4*)&Bs[kk][tc * 4];
            float aa[4] = {a4.x, a4.y, a4.z, a4.w};
            float bb[4] = {b4.x, b4.y, b4.z, b4.w};
            #pragma unroll
            for (int i = 0; i < 4; ++i)
                #pragma unroll
                for (int j = 0; j < 4; ++j)
                    acc[i][j] = fmaf(aa[i], bb[j], acc[i][j]);
        }
        __syncthreads();
    }

    #pragma unroll
    for (int i = 0; i < 4; ++i) {
        int m = bm + tr * 4 + i;
        #pragma unroll
        for (int j = 0; j < 4; ++j) {
            int n = bn + tc * 4 + j;
            int b  = m >> 10, s = m & 1023;
            int hh = n >> 6,  d = n & 63;
            C[(((size_t)b * HDIM + hh) * SDIM + s) * HD + d] = acc[i][j];
        }
    }
}

// ---------------- eta = sigmoid(h @ lr_w + lr_b) / hd  (per-row block) -----
__global__ __launch_bounds__(192) void eta_kernel(
    const float* __restrict__ h, const float* __restrict__ lr_w,
    const float* __restrict__ lr_b, float* __restrict__ etab)
{
    const int row = blockIdx.x, tid = threadIdx.x, wave = tid >> 6;
    __shared__ float part[3][3];   // [wave][hh]
    float hv = h[(size_t)row * ADIM + tid];
    float p0 = hv * lr_w[tid * 3 + 0];
    float p1 = hv * lr_w[tid * 3 + 1];
    float p2 = hv * lr_w[tid * 3 + 2];
    float s0 = wave_bcast_sum(p0);
    float s1 = wave_bcast_sum(p1);
    float s2 = wave_bcast_sum(p2);
    if ((tid & 63) == 0) {
        part[wave][0] = s0; part[wave][1] = s1; part[wave][2] = s2;
    }
    __syncthreads();
    if (tid < 3) {
        float acc = (part[0][tid] + part[1][tid]) + part[2][tid] + lr_b[tid];
        float e = 1.f / (1.f + __expf(-acc)) * (1.f / 64.f);
        int b = row >> 10, s = row & 1023;
        etab[((size_t)(b * HDIM + tid)) * SDIM + s] = e;
    }
}

// -- pre: A=[k.k+1], B=[q.k+1], a-vectors (into vb), r6 ----------------------
__global__ __launch_bounds__(256) void ab_kernel(
    const float* __restrict__ qb, const float* __restrict__ kb,
    float* __restrict__ vb,            // in: v; out: a = (bw-(v-k))*gw
    const float* __restrict__ ttt_g, const float* __restrict__ ttt_b,
    float* __restrict__ Ab, float* __restrict__ Bb,
    float* __restrict__ r6b)
{
    int bh = blockIdx.x >> 5, c = blockIdx.x & 31, cs = c * 32;
    int hh = bh % HDIM;
    __shared__ float Kc[32][65], Qc[32][65], Vc[32][65];
    for (int i = threadIdx.x; i < 2048; i += 256) {
        int t = i >> 6, j = i & 63;
        Kc[t][j] = kb[((size_t)bh * SDIM + cs + t) * HD + j];
        Qc[t][j] = qb[((size_t)bh * SDIM + cs + t) * HD + j];
        Vc[t][j] = vb[((size_t)bh * SDIM + cs + t) * HD + j];
    }
    __syncthreads();
    size_t base = ((size_t)(bh * NCHUNK + c)) * 1024;
    for (int e = threadIdx.x; e < 1024; e += 256) {
        int t = e >> 5, s = e & 31;
        float a = 1.f, b = 1.f;
        #pragma unroll
        for (int j = 0; j < 64; ++j) {
            float ks = Kc[s][j];
            a = fmaf(Kc[t][j], ks, a);
            b = fmaf(Qc[t][j], ks, b);
        }
        Ab[base + e] = a;
        Bb[base + e] = b;
    }
    for (int i = threadIdx.x; i < 2048; i += 256) {
        int t = i >> 6, j = i & 63;
        float gwv = ttt_g[hh * 64 + j], bwv = ttt_b[hh * 64 + j];
        float av = fmaf(-(Vc[t][j] - Kc[t][j]), gwv, bwv * gwv);
        Vc[t][j] = av;
        vb[((size_t)bh * SDIM + cs + t) * HD + j] = av;
    }
    __syncthreads();
    if (threadIdx.x < 32) {
        int t = threadIdx.x;
        float acc = 0.f;
        #pragma unroll
        for (int j = 0; j < 64; ++j) acc += Vc[t][j];
        r6b[(size_t)bh * SDIM + cs + t] = acc;
    }
}

// ---------------- staging helper (global -> LDS, float4) -------------------
__device__ __forceinline__ void stage_chunk(
    int pp, int cc, int bh, int idx, int nth,
    const float* __restrict__ kbuf, const float* __restrict__ abuf,
    const float* __restrict__ Ab, const float* __restrict__ etab,
    const float* __restrict__ r6b,
    float4* K4, float4* a4, float4* A4, float2* er6)
{
    const float4* kg = (const float4*)(kbuf + ((size_t)bh * SDIM + cc * 32) * HD);
    const float4* ag = (const float4*)(abuf + ((size_t)bh * SDIM + cc * 32) * HD);
    const float4* Ag = (const float4*)(Ab + ((size_t)(bh * NCHUNK + cc)) * 1024);
    for (int i = idx; i < 512; i += nth) K4[pp * 512 + i] = kg[i];
    for (int i = idx; i < 512; i += nth) a4[pp * 512 + i] = ag[i];
    for (int i = idx; i < 256; i += nth) A4[pp * 256 + i] = Ag[i];
    for (int i = idx; i < 32; i += nth)
        er6[pp * 32 + i] = make_float2(
            etab[(size_t)bh * SDIM + cc * 32 + i] * (1.f / 64.f),
            r6b[(size_t)bh * SDIM + cc * 32 + i]);
}

// ---------------- the sequential TTT scan (12 blocks) ----------------------
// r11: ROLLED token/P1/P3 loops so the 32-iteration chunk-loop body fits I$
// (~3 KB vs ~33 KB unrolled). Z future-token state kept in registers via
// rotation: iteration I does Z[j-1] = fma(-A[row][row+j], ge, Z[j]) with
// compile-time j (ascending order is WAR-safe; garbage entering at the top
// slot provably never reaches slot 0 within 16 iterations; A-row over-reads
// stay inside the LDS block and finite). Critical path per token unchanged.
__global__ __launch_bounds__(256, 1) void ttt_scan(
    const float* __restrict__ kbuf, const float* __restrict__ abuf,
    const float* __restrict__ etab, const float* __restrict__ Ab,
    const float* __restrict__ r6b,
    const float* __restrict__ W1,   const float* __restrict__ b1,
    const float* __restrict__ ttt_g, const float* __restrict__ ttt_b,
    float* __restrict__ Gbuf, float* __restrict__ W0save, float* __restrict__ b0save)
{
    const int bh = blockIdx.x, hh = bh % HDIM;
    const int tid = threadIdx.x, lane = tid & 63;
    const int wv = tid >> 6;
    __shared__ float  Zp[4][16][64];   // 16 KB: per-wave Z0 partials
    __shared__ float4 K4s[2 * 512];    // 16 KB: K double-buffered
    __shared__ float4 a4s[2 * 512];    // 16 KB: a double-buffered
    __shared__ float4 A4s[2 * 256];    //  8 KB: A double-buffered
    __shared__ float2 er6s[2 * 32];    // 512 B
    __shared__ float  Gl[16][64];      //  4 KB: per-token eta*g (sub-chunk)

    float Wreg[16];
    #pragma unroll
    for (int r = 0; r < 16; ++r)
        Wreg[r] = W1[hh * 4096 + (wv * 16 + r) * 64 + lane];
    float breg = b1[hh * 64 + lane];
    const float gw = ttt_g[hh * 64 + lane];
    const float w3 = gw * gw;
    const float Cg2 = wave_bcast_sum(w3);
    const float* a_f = (const float*)a4s;
    const float* A_f = (const float*)A4s;

    stage_chunk(0, 0, bh, tid, 256, kbuf, abuf, Ab, etab, r6b,
                K4s, a4s, A4s, er6s);
    __syncthreads();

    #pragma unroll 1
    for (int c = 0; c < NCHUNK; ++c) {
        const int p = c & 1;

        {
            float* Wd = W0save + ((size_t)(bh * NCHUNK + c)) * 4096
                        + (wv * 16) * 64 + lane;
            #pragma unroll
            for (int r = 0; r < 16; ++r) Wd[r * 64] = Wreg[r];
            if (tid < 64) b0save[(bh * NCHUNK + c) * 64 + tid] = breg;
        }

        #pragma unroll 1
        for (int h = 0; h < 2; ++h) {
            const int h16 = h * 16;

            // ---- P1 (all waves, rolled): Zp[wv][i] = partial K@W ---------
            #pragma unroll 1
            for (int i = 0; i < 16; ++i) {
                const int t = h16 + i;
                float zt = 0.f;
                #pragma unroll
                for (int r4 = 0; r4 < 4; ++r4) {
                    const float4 kv = K4s[p * 512 + t * 16 + wv * 4 + r4];
                    zt = fmaf(kv.x, Wreg[r4 * 4 + 0], zt);
                    zt = fmaf(kv.y, Wreg[r4 * 4 + 1], zt);
                    zt = fmaf(kv.z, Wreg[r4 * 4 + 2], zt);
                    zt = fmaf(kv.w, Wreg[r4 * 4 + 3], zt);
                }
                Zp[wv][i][lane] = zt;
            }
            __syncthreads();   // (A) Zp ready; buffer p staged

            // ---- P2: wave 0 serial; waves 1-3 stage next chunk (h==0) ----
            if (wv == 0) {
                float Z[16];
                #pragma unroll
                for (int i = 0; i < 16; ++i)
                    Z[i] = ((Zp[0][i][lane] + Zp[1][i][lane]) +
                            (Zp[2][i][lane] + Zp[3][i][lane])) + breg;
                float aC  = a_f[p * 2048 + h16 * 64 + lane];
                float2 erC = er6s[p * 32 + h16];
                #pragma unroll 1
                for (int I = 0; I < 16; ++I) {
                    // shifted A-row (row r, cols r+1..r+15), lane-uniform,
                    // 15 x ds_read_b32 off one base; consumed ~150cy later
                    const int arow = p * 1024 + (h16 + I) * 33;
                    float Aj[16];
                    #pragma unroll
                    for (int j = 1; j < 16; ++j) Aj[j] = A_f[arow + j];
                    const int nI = (I < 15) ? I + 1 : 15;
                    float aN   = a_f[p * 2048 + (h16 + nI) * 64 + lane];
                    float2 erN = er6s[p * 32 + h16 + nI];

                    float z  = Z[0];
                    float a  = aC;
                    float zg = z * w3;
                    float x1 = z, x2 = z * z, x3 = zg, x4 = zg * z, x5 = z * a;
                    red5_asm(x1, x2, x3, x4, x5);
                    float r1 = rl(x1, 63), r2 = rl(x2, 63), r3 = rl(x3, 63);
                    float r4 = rl(x4, 63), r5 = rl(x5, 63);
                    float r6t = erC.y;
                    float mu   = r1 * (1.f / 64.f);
                    float var  = fmaf(-mu, mu, r2 * (1.f / 64.f));
                    float rstd = fast_rsq(var + EPSLN);
                    float mc   = mu * Cg2;
                    float sgxh = fmaf(rstd, r3 - mc, r6t);
                    float t4v  = fmaf(mu, mc, fmaf(-2.f * mu, r3, r4));
                    float sgz  = fmaf(rstd * rstd, t4v, rstd * (r5 - mu * r6t));
                    float zh   = (z - mu) * rstd;
                    float gxh  = fmaf(zh, w3, a);
                    float ge   = (fmaf(64.f, gxh, -sgxh) - zh * sgz)
                                 * (rstd * erC.x);
                    Gl[I][lane] = ge;
                    // rotate-update: ascending j => WAR-safe shift-down
                    #pragma unroll
                    for (int j = 1; j < 16; ++j)
                        Z[j - 1] = fmaf(-Aj[j], ge, Z[j]);
                    aC = aN; erC = erN;
                }
            } else if (h == 0 && c < NCHUNK - 1) {
                stage_chunk(p ^ 1, c + 1, bh, tid - 64, 192,
                            kbuf, abuf, Ab, etab, r6b, K4s, a4s, A4s, er6s);
            }
            __syncthreads();   // (B) Gl ready; staging (h==0) done

            // ---- P3 (all waves, rolled): W -= K^T@G ; b -= colsum(G) -----
            float btot = 0.f;
            #pragma unroll 1
            for (int s = 0; s < 16; ++s) {
                float gd = Gl[s][lane];
                btot += gd;
                #pragma unroll
                for (int r4 = 0; r4 < 4; ++r4) {
                    const float4 kv = K4s[p * 512 + (h16 + s) * 16 + wv * 4 + r4];
                    Wreg[r4 * 4 + 0] = fmaf(-kv.x, gd, Wreg[r4 * 4 + 0]);
                    Wreg[r4 * 4 + 1] = fmaf(-kv.y, gd, Wreg[r4 * 4 + 1]);
                    Wreg[r4 * 4 + 2] = fmaf(-kv.z, gd, Wreg[r4 * 4 + 2]);
                    Wreg[r4 * 4 + 3] = fmaf(-kv.w, gd, Wreg[r4 * 4 + 3]);
                }
            }
            breg -= btot;
            {
                float* gb = Gbuf + ((size_t)bh * SDIM + c * 32 + h16) * HD + lane;
                #pragma unroll
                for (int r = 0; r < 4; ++r)
                    gb[(wv * 4 + r) * HD] = Gl[wv * 4 + r][lane];
            }
        }
    }
}

// ---------------- post: Zq = Qc@W0 + b0 - tril(B)@G ; ys = q + ln(Zq) ------
__global__ __launch_bounds__(256) void post_kernel(
    const float* __restrict__ qbuf, const float* __restrict__ Bb,
    const float* __restrict__ Gbuf, const float* __restrict__ W0save,
    const float* __restrict__ b0save,
    const float* __restrict__ ttt_g, const float* __restrict__ ttt_b,
    float* __restrict__ ys)
{
    const int bh = blockIdx.x >> 5, c = blockIdx.x & 31, cs = c * 32;
    const int b = bh / HDIM, hh = bh % HDIM;
    const int tid = threadIdx.x, lane = tid & 63, wave = tid >> 6;
    __shared__ float Qc[32][65];
    __shared__ float W0l[64][65];
    __shared__ float Gl[32][64];
    for (int i = tid; i < 2048; i += 256) {
        int t = i >> 6, j = i & 63;
        Qc[t][j] = qbuf[((size_t)bh * SDIM + cs + t) * HD + j];
        Gl[t][j] = Gbuf[((size_t)bh * SDIM + cs + t) * HD + j];
    }
    for (int i = tid; i < 4096; i += 256)
        W0l[i >> 6][i & 63] = W0save[((size_t)(bh * NCHUNK + c)) * 4096 + i];
    __syncthreads();

    const float bb0 = b0save[(bh * NCHUNK + c) * 64 + lane];
    const float gw = ttt_g[hh * 64 + lane], bw = ttt_b[hh * 64 + lane];
    float acc[8];
    #pragma unroll
    for (int r = 0; r < 8; ++r) acc[r] = bb0;
    for (int j = 0; j < 64; ++j) {
        float w0 = W0l[j][lane];
        #pragma unroll
        for (int r = 0; r < 8; ++r)
            acc[r] = fmaf(Qc[wave * 8 + r][j], w0, acc[r]);
    }
    float Breg[8];
    size_t bbase = ((size_t)(bh * NCHUNK + c)) * 1024;
    #pragma unroll
    for (int r = 0; r < 8; ++r)
        Breg[r] = Bb[bbase + (wave * 8 + r) * 32 + (lane & 31)];
    #pragma unroll
    for (int s = 0; s < 32; ++s) {
        float gd = Gl[s][lane];
        #pragma unroll
        for (int r = 0; r < 8; ++r) {
            int t = wave * 8 + r;
            float Bts = rl(Breg[r], s);
            acc[r] = (s <= t) ? fmaf(-Bts, gd, acc[r]) : acc[r];
        }
    }
    #pragma unroll
    for (int r = 0; r < 8; ++r) {
        int t = wave * 8 + r;
        float s1 = wave_bcast_sum(acc[r]);
        float s2 = wave_bcast_sum(acc[r] * acc[r]);
        float mu = s1 * (1.f / 64.f);
        float var = s2 * (1.f / 64.f) - mu * mu;
        float rstd = rsqrtf(var + EPSLN);
        float zh = (acc[r] - mu) * rstd;
        float val = zh * gw + bw + Qc[t][lane];
        ys[((size_t)(b * SDIM) + cs + t) * ADIM + hh * HD + lane] = val;
    }
}

// ---------------- launch ---------------------------------------------------
extern "C" void kernel_launch(void* const* d_in, const int* in_sizes, int n_in,
                              void* d_out, int out_size, void* d_ws, size_t ws_size,
                              hipStream_t stream)
{
    const float* x      = (const float*)d_in[0];
    const float* W_down = (const float*)d_in[1];
    const float* b_down = (const float*)d_in[2];
    const float* Wq     = (const float*)d_in[3];
    const float* Wk     = (const float*)d_in[4];
    const float* Wv     = (const float*)d_in[5];
    const float* Wo     = (const float*)d_in[6];
    const float* W1     = (const float*)d_in[7];
    const float* b1     = (const float*)d_in[8];
    const float* ttt_g  = (const float*)d_in[9];
    const float* ttt_b  = (const float*)d_in[10];
    const float* lr_w   = (const float*)d_in[11];
    const float* lr_b   = (const float*)d_in[12];
    const float* post_g = (const float*)d_in[13];
    const float* post_b = (const float*)d_in[14];
    const float* norm_g = (const float*)d_in[15];
    const float* norm_b = (const float*)d_in[16];
    const float* W_up   = (const float*)d_in[17];
    const float* b_up   = (const float*)d_in[18];
    float* out = (float*)d_out;

    float* ws = (float*)d_ws;
    const size_t SZ = (size_t)MROWS * ADIM;      // 786432
    float* h    = ws;                // [4096][192]
    float* qb   = ws + SZ;           // [12][1024][64]
    float* kb   = ws + 2 * SZ;
    float* vb   = ws + 3 * SZ;       // after ab_kernel: a-vectors
    float* Gb   = ws + 4 * SZ;
    float* etab = ws + 5 * SZ;                       // 12288
    float* Ab   = etab + 12288;                      // 393216
    float* Bb   = Ab + 393216;                       // 393216
    float* W0s  = Bb + 393216;                       // 1572864
    float* b0s  = W0s + 1572864;                     // 24576
    float* r6b  = b0s + 24576;                       // 12288
    float2* lnst = (float2*)(r6b + 12288);           // 4096 float2
    // aliases (lifetime-disjoint)
    float* ysb  = h;    // post_kernel output (h dead after eta)
    float* tbuf = qb;   // ln(ys)@Wo (qb dead after post_kernel)

    // 1) h = silu(x @ W_down + b_down)
    gemm_k<1, 0, 0><<<dim3(ADIM / 64, MROWS / 64), 256, 0, stream>>>(
        x, W_down, b_down, h, MROWS, ADIM, DDIM, nullptr, nullptr, nullptr);
    // 2) q,k,v in ONE launch
    gemm_qkv<<<dim3(ADIM / 64, MROWS / 64, 3), 256, 0, stream>>>(
        h, Wq, Wk, Wv, qb);
    // 3) eta (per-row coalesced)
    eta_kernel<<<MROWS, 192, 0, stream>>>(h, lr_w, lr_b, etab);
    // 4) chunk coefficient matrices + a-vectors (in vb) + r6
    ab_kernel<<<BDIM * HDIM * NCHUNK, 256, 0, stream>>>(
        qb, kb, vb, ttt_g, ttt_b, Ab, Bb, r6b);
    // 5) sequential scan (rolled, I$-resident)
    ttt_scan<<<BDIM * HDIM, 256, 0, stream>>>(
        kb, vb, etab, Ab, r6b, W1, b1, ttt_g, ttt_b, Gb, W0s, b0s);
    // 6) outputs ys = q + ln(Zq)
    post_kernel<<<BDIM * HDIM * NCHUNK, 256, 0, stream>>>(
        qb, Bb, Gb, W0s, b0s, ttt_g, ttt_b, ysb);
    // 7) t = ln(ys) @ Wo   (LN fused into GEMM A-load)
    lnstats<<<MROWS, 64, 0, stream>>>(ysb, lnst);
    gemm_k<0, 0, 1><<<dim3(ADIM / 64, MROWS / 64), 256, 0, stream>>>(
        ysb, Wo, nullptr, tbuf, MROWS, ADIM, ADIM, lnst, post_g, post_b);
    // 8) out = ln(t) @ W_up + b_up   (LN fused into GEMM A-load)
    lnstats<<<MROWS, 64, 0, stream>>>(tbuf, lnst);
    gemm_k<0, 0, 1><<<dim3(DDIM / 64, MROWS / 64), 256, 0, stream>>>(
        tbuf, W_up, b_up, out, MROWS, DDIM, ADIM, lnst, norm_g, norm_b);
}

// Round 3
// 580.792 us; speedup vs baseline: 1.0542x; 1.0542x over previous
//
#include <hip/hip_runtime.h>
#include <hip/hip_bf16.h>
#include <math.h>

// Problem shape (fixed): B=4, S=1024, D=768, A=192, H=3, hd=64
#define BDIM 4
#define SDIM 1024
#define DDIM 768
#define ADIM 192
#define HDIM 3
#define HD   64
#define MROWS (BDIM*SDIM)      // 4096
#define NCHUNK (SDIM/32)       // 32
#define EPSLN 1e-6f

// ---------------- DPP wave reduction (64-lane sum, result broadcast) -------
template<int CTRL, int RMASK, bool BC>
__device__ __forceinline__ float dpp_add_step(float x) {
    int t = __builtin_amdgcn_update_dpp(0, __float_as_int(x), CTRL, RMASK, 0xf, BC);
    return x + __int_as_float(t);
}
__device__ __forceinline__ float wave_bcast_sum(float x) {
    x = dpp_add_step<0x111, 0xf, true >(x);
    x = dpp_add_step<0x112, 0xf, true >(x);
    x = dpp_add_step<0x114, 0xf, true >(x);
    x = dpp_add_step<0x118, 0xf, true >(x);
    x = dpp_add_step<0x142, 0xa, false>(x);
    x = dpp_add_step<0x143, 0xc, false>(x);
    return __int_as_float(__builtin_amdgcn_readlane(__float_as_int(x), 63));
}
__device__ __forceinline__ float rl(float v, int lane) {
    return __int_as_float(__builtin_amdgcn_readlane(__float_as_int(v), lane));
}
__device__ __forceinline__ float fast_rsq(float x) {
    float r;
    asm("v_rsq_f32 %0, %1" : "=v"(r) : "v"(x));
    return r;
}
// 5 simultaneous 64-lane sums via fused DPP adds (validated r7-r10).
__device__ __forceinline__ void red5_asm(float& a, float& b, float& c,
                                         float& d, float& e) {
#define R5_SHR(N)                                                              \
    asm("v_add_f32 %0, %0, %0 row_shr:" #N " row_mask:0xf bank_mask:0xf bound_ctrl:0" : "+v"(a)); \
    asm("v_add_f32 %0, %0, %0 row_shr:" #N " row_mask:0xf bank_mask:0xf bound_ctrl:0" : "+v"(b)); \
    asm("v_add_f32 %0, %0, %0 row_shr:" #N " row_mask:0xf bank_mask:0xf bound_ctrl:0" : "+v"(c)); \
    asm("v_add_f32 %0, %0, %0 row_shr:" #N " row_mask:0xf bank_mask:0xf bound_ctrl:0" : "+v"(d)); \
    asm("v_add_f32 %0, %0, %0 row_shr:" #N " row_mask:0xf bank_mask:0xf bound_ctrl:0" : "+v"(e));
#define R5_BC(N, RM)                                                           \
    asm("v_add_f32 %0, %0, %0 row_bcast:" #N " row_mask:" #RM " bank_mask:0xf" : "+v"(a)); \
    asm("v_add_f32 %0, %0, %0 row_bcast:" #N " row_mask:" #RM " bank_mask:0xf" : "+v"(b)); \
    asm("v_add_f32 %0, %0, %0 row_bcast:" #N " row_mask:" #RM " bank_mask:0xf" : "+v"(c)); \
    asm("v_add_f32 %0, %0, %0 row_bcast:" #N " row_mask:" #RM " bank_mask:0xf" : "+v"(d)); \
    asm("v_add_f32 %0, %0, %0 row_bcast:" #N " row_mask:" #RM " bank_mask:0xf" : "+v"(e));
    R5_SHR(1) R5_SHR(2) R5_SHR(4) R5_SHR(8)
    R5_BC(15, 0xa) R5_BC(31, 0xc)
#undef R5_SHR
#undef R5_BC
}

// ---------------- per-row LayerNorm stats: (mu, rstd) over 192 -------------
__global__ __launch_bounds__(64) void lnstats(
    const float* __restrict__ in, float2* __restrict__ st)
{
    int row = blockIdx.x, tid = threadIdx.x;
    float x0 = in[(size_t)row * ADIM + tid];
    float x1 = in[(size_t)row * ADIM + 64 + tid];
    float x2 = in[(size_t)row * ADIM + 128 + tid];
    float s1 = wave_bcast_sum((x0 + x1) + x2);
    float s2 = wave_bcast_sum(fmaf(x0, x0, fmaf(x1, x1, x2 * x2)));
    if (tid == 0) {
        float mu = s1 * (1.f / 192.f);
        float var = s2 * (1.f / 192.f) - mu * mu;
        st[row] = make_float2(mu, rsqrtf(var + EPSLN));
    }
}

// ---------------- Generic fp32 tiled GEMM: C = act(lnA(A)@B + bias) --------
template<int ACT, int LAYOUT, int LNA>
__global__ __launch_bounds__(256) void gemm_k(
    const float* __restrict__ A, const float* __restrict__ Bm,
    const float* __restrict__ bias, float* __restrict__ C,
    int M, int N, int K,
    const float2* __restrict__ lnst, const float* __restrict__ lng,
    const float* __restrict__ lnbb)
{
    __shared__ float As[16][68];
    __shared__ float Bs[16][68];
    const int tid = threadIdx.x;
    const int bm = blockIdx.y * 64, bn = blockIdx.x * 64;
    const int tr = tid >> 4, tc = tid & 15;
    float acc[4][4] = {};

    for (int k0 = 0; k0 < K; k0 += 16) {
        #pragma unroll
        for (int p = 0; p < 4; ++p) {
            int m = (tid >> 4) + p * 16;
            int kk = tid & 15;
            float av = A[(size_t)(bm + m) * K + k0 + kk];
            if (LNA) {
                float2 stv = lnst[bm + m];
                av = fmaf((av - stv.x) * stv.y, lng[k0 + kk], lnbb[k0 + kk]);
            }
            As[kk][m] = av;
        }
        #pragma unroll
        for (int p = 0; p < 4; ++p) {
            int kk = (tid >> 6) + p * 4;
            int n = tid & 63;
            Bs[kk][n] = Bm[(size_t)(k0 + kk) * N + bn + n];
        }
        __syncthreads();
        #pragma unroll
        for (int kk = 0; kk < 16; ++kk) {
            // 16B-aligned: As row stride 272B, offsets are multiples of 16B
            const float4 a4 = *(const float4*)&As[kk][tr * 4];
            const float4 b4 = *(const float4*)&Bs[kk][tc * 4];
            float aa[4] = {a4.x, a4.y, a4.z, a4.w};
            float bb[4] = {b4.x, b4.y, b4.z, b4.w};
            #pragma unroll
            for (int i = 0; i < 4; ++i)
                #pragma unroll
                for (int j = 0; j < 4; ++j)
                    acc[i][j] = fmaf(aa[i], bb[j], acc[i][j]);
        }
        __syncthreads();
    }

    #pragma unroll
    for (int i = 0; i < 4; ++i) {
        int m = bm + tr * 4 + i;
        #pragma unroll
        for (int j = 0; j < 4; ++j) {
            int n = bn + tc * 4 + j;
            float v = acc[i][j];
            if (bias) v += bias[n];
            if (ACT == 1) v = v / (1.f + __expf(-v));   // silu
            if (LAYOUT == 0) {
                C[(size_t)m * N + n] = v;
            } else {
                int b  = m >> 10, s = m & 1023;
                int hh = n >> 6,  d = n & 63;
                C[(((size_t)b * HDIM + hh) * SDIM + s) * HD + d] = v;
            }
        }
    }
}

// ---------------- fused QKV GEMM: one launch, blockIdx.z picks the head ----
__global__ __launch_bounds__(256) void gemm_qkv(
    const float* __restrict__ A, const float* __restrict__ BWq,
    const float* __restrict__ BWk, const float* __restrict__ BWv,
    float* __restrict__ Cbase)
{
    const float* Bm = (blockIdx.z == 0) ? BWq : (blockIdx.z == 1) ? BWk : BWv;
    float* C = Cbase + (size_t)blockIdx.z * ((size_t)MROWS * ADIM);
    __shared__ float As[16][68];
    __shared__ float Bs[16][68];
    const int tid = threadIdx.x;
    const int bm = blockIdx.y * 64, bn = blockIdx.x * 64;
    const int tr = tid >> 4, tc = tid & 15;
    float acc[4][4] = {};

    for (int k0 = 0; k0 < ADIM; k0 += 16) {
        #pragma unroll
        for (int p = 0; p < 4; ++p) {
            int m = (tid >> 4) + p * 16;
            int kk = tid & 15;
            As[kk][m] = A[(size_t)(bm + m) * ADIM + k0 + kk];
        }
        #pragma unroll
        for (int p = 0; p < 4; ++p) {
            int kk = (tid >> 6) + p * 4;
            int n = tid & 63;
            Bs[kk][n] = Bm[(size_t)(k0 + kk) * ADIM + bn + n];
        }
        __syncthreads();
        #pragma unroll
        for (int kk = 0; kk < 16; ++kk) {
            const float4 a4 = *(const float4*)&As[kk][tr * 4];
            const float4 b4 = *(const float4*)&Bs[kk][tc * 4];
            float aa[4] = {a4.x, a4.y, a4.z, a4.w};
            float bb[4] = {b4.x, b4.y, b4.z, b4.w};
            #pragma unroll
            for (int i = 0; i < 4; ++i)
                #pragma unroll
                for (int j = 0; j < 4; ++j)
                    acc[i][j] = fmaf(aa[i], bb[j], acc[i][j]);
        }
        __syncthreads();
    }

    #pragma unroll
    for (int i = 0; i < 4; ++i) {
        int m = bm + tr * 4 + i;
        #pragma unroll
        for (int j = 0; j < 4; ++j) {
            int n = bn + tc * 4 + j;
            int b  = m >> 10, s = m & 1023;
            int hh = n >> 6,  d = n & 63;
            C[(((size_t)b * HDIM + hh) * SDIM + s) * HD + d] = acc[i][j];
        }
    }
}

// ------- eta = sigmoid(h @ lr_w + lr_b)/(64*64) -> er6b[.].x ---------------
// (folds the staging-time extra 1/64 that ttt_scan's TOK formula expects)
__global__ __launch_bounds__(192) void eta_kernel(
    const float* __restrict__ h, const float* __restrict__ lr_w,
    const float* __restrict__ lr_b, float2* __restrict__ er6b)
{
    const int row = blockIdx.x, tid = threadIdx.x, wave = tid >> 6;
    __shared__ float part[3][3];   // [wave][hh]
    float hv = h[(size_t)row * ADIM + tid];
    float p0 = hv * lr_w[tid * 3 + 0];
    float p1 = hv * lr_w[tid * 3 + 1];
    float p2 = hv * lr_w[tid * 3 + 2];
    float s0 = wave_bcast_sum(p0);
    float s1 = wave_bcast_sum(p1);
    float s2 = wave_bcast_sum(p2);
    if ((tid & 63) == 0) {
        part[wave][0] = s0; part[wave][1] = s1; part[wave][2] = s2;
    }
    __syncthreads();
    if (tid < 3) {
        float acc = (part[0][tid] + part[1][tid]) + part[2][tid] + lr_b[tid];
        float e = 1.f / (1.f + __expf(-acc)) * (1.f / 4096.f);
        int b = row >> 10, s = row & 1023;
        er6b[(size_t)(b * HDIM + tid) * SDIM + s].x = e;
    }
}

// -- pre: A=[k.k+1], B=[q.k+1], a-vectors (into vb), r6 -> er6b[.].y ---------
__global__ __launch_bounds__(256) void ab_kernel(
    const float* __restrict__ qb, const float* __restrict__ kb,
    float* __restrict__ vb,            // in: v; out: a = (bw-(v-k))*gw
    const float* __restrict__ ttt_g, const float* __restrict__ ttt_b,
    float* __restrict__ Ab, float* __restrict__ Bb,
    float2* __restrict__ er6b)
{
    int bh = blockIdx.x >> 5, c = blockIdx.x & 31, cs = c * 32;
    int hh = bh % HDIM;
    __shared__ float Kc[32][65], Qc[32][65], Vc[32][65];
    for (int i = threadIdx.x; i < 2048; i += 256) {
        int t = i >> 6, j = i & 63;
        Kc[t][j] = kb[((size_t)bh * SDIM + cs + t) * HD + j];
        Qc[t][j] = qb[((size_t)bh * SDIM + cs + t) * HD + j];
        Vc[t][j] = vb[((size_t)bh * SDIM + cs + t) * HD + j];
    }
    __syncthreads();
    size_t base = ((size_t)(bh * NCHUNK + c)) * 1024;
    for (int e = threadIdx.x; e < 1024; e += 256) {
        int t = e >> 5, s = e & 31;
        float a = 1.f, b = 1.f;
        #pragma unroll
        for (int j = 0; j < 64; ++j) {
            float ks = Kc[s][j];
            a = fmaf(Kc[t][j], ks, a);
            b = fmaf(Qc[t][j], ks, b);
        }
        Ab[base + e] = a;
        Bb[base + e] = b;
    }
    for (int i = threadIdx.x; i < 2048; i += 256) {
        int t = i >> 6, j = i & 63;
        float gwv = ttt_g[hh * 64 + j], bwv = ttt_b[hh * 64 + j];
        float av = fmaf(-(Vc[t][j] - Kc[t][j]), gwv, bwv * gwv);
        Vc[t][j] = av;
        vb[((size_t)bh * SDIM + cs + t) * HD + j] = av;
    }
    __syncthreads();
    if (threadIdx.x < 32) {
        int t = threadIdx.x;
        float acc = 0.f;
        #pragma unroll
        for (int j = 0; j < 64; ++j) acc += Vc[t][j];
        er6b[(size_t)bh * SDIM + cs + t].y = acc;
    }
}

// ---------------- staging helper (global -> LDS, float4): K and A only -----
__device__ __forceinline__ void stage_chunk(
    int pp, int cc, int bh, int idx, int nth,
    const float* __restrict__ kbuf, const float* __restrict__ Ab,
    float4* K4, float4* A4)
{
    const float4* kg = (const float4*)(kbuf + ((size_t)bh * SDIM + cc * 32) * HD);
    const float4* Ag = (const float4*)(Ab + ((size_t)(bh * NCHUNK + cc)) * 1024);
    for (int i = idx; i < 512; i += nth) K4[pp * 512 + i] = kg[i];
    for (int i = idx; i < 256; i += nth) A4[pp * 256 + i] = Ag[i];
}

// ---------------- the sequential TTT scan (12 blocks) ----------------------
// r13: merged 32-token serial pass (r12 logic, which is the exact linear
// reassociation r10 used within halves + W-routing; post_kernel already
// validates the same 32-token form). LDS cut 82432 -> 57344 B to fit the
// 64 KiB static-shared launch limit (the r12 NaN = failed launch theory):
//   - Zp [3][32][64] (dropped unused slice 0)
//   - a-vectors and (eta,r6) read straight from global by wave 0 with the
//     existing one-token prefetch distance (offsets fold to immediates).
__global__ __launch_bounds__(256, 1) void ttt_scan(
    const float* __restrict__ kbuf, const float* __restrict__ abuf,
    const float2* __restrict__ er6b, const float* __restrict__ Ab,
    const float* __restrict__ W1,   const float* __restrict__ b1,
    const float* __restrict__ ttt_g, const float* __restrict__ ttt_b,
    float* __restrict__ Gbuf, float* __restrict__ W0save, float* __restrict__ b0save)
{
    const int bh = blockIdx.x, hh = bh % HDIM;
    const int tid = threadIdx.x, lane = tid & 63;
    const int wv = tid >> 6;
    __shared__ float  Zp[3][32][64];   // 24 KB: waves 1-3 Z0 partials
    __shared__ float4 K4s[2 * 512];    // 16 KB: K double-buffered
    __shared__ float4 A4s[2 * 256];    //  8 KB: A double-buffered
    __shared__ float  Gl[32][64];      //  8 KB: per-token eta*g (full chunk)

    float Wreg[16];
    #pragma unroll
    for (int r = 0; r < 16; ++r)
        Wreg[r] = W1[hh * 4096 + (wv * 16 + r) * 64 + lane];
    float breg = b1[hh * 64 + lane];
    const float gw = ttt_g[hh * 64 + lane];
    const float bw = ttt_b[hh * 64 + lane];
    const float w3 = gw * gw;
    (void)bw;
    const float Cg2 = wave_bcast_sum(w3);

    stage_chunk(0, 0, bh, tid, 256, kbuf, Ab, K4s, A4s);
    __syncthreads();

    for (int c = 0; c < NCHUNK; ++c) {
        const int cs = c * 32;
        const int p = c & 1;

        {
            float* Wd = W0save + ((size_t)(bh * NCHUNK + c)) * 4096
                        + (wv * 16) * 64 + lane;
            #pragma unroll
            for (int r = 0; r < 16; ++r) Wd[r * 64] = Wreg[r];
            if (tid < 64) b0save[(bh * NCHUNK + c) * 64 + tid] = breg;
        }

        // ---- P1 (all waves): Z0 partials for all 32 tokens ---------------
        float Z[32];
        #pragma unroll
        for (int i = 0; i < 32; ++i) {
            float zt = 0.f;
            #pragma unroll
            for (int r4 = 0; r4 < 4; ++r4) {
                const float4 kv = K4s[p * 512 + i * 16 + wv * 4 + r4];
                zt = fmaf(kv.x, Wreg[r4 * 4 + 0], zt);
                zt = fmaf(kv.y, Wreg[r4 * 4 + 1], zt);
                zt = fmaf(kv.z, Wreg[r4 * 4 + 2], zt);
                zt = fmaf(kv.w, Wreg[r4 * 4 + 3], zt);
            }
            if (wv != 0) Zp[wv - 1][i][lane] = zt;
            else         Z[i] = zt;
        }
        __syncthreads();   // (A) Zp ready; buffer p staged

        // ---- P2: wave 0 serial over 32 tokens; waves 1-3 stage next ------
        if (wv == 0) {
            const float*  ag = abuf + ((size_t)bh * SDIM + cs) * HD;
            const float2* eg = er6b + (size_t)bh * SDIM + cs;
            float  aA = ag[lane];      // token 0 (latency hides under combine)
            float2 erA = eg[0];
            float  aB; float2 erB;
            #pragma unroll
            for (int i = 0; i < 32; ++i)
                Z[i] = ((Z[i] + Zp[0][i][lane]) +
                        (Zp[1][i][lane] + Zp[2][i][lane])) + breg;
            float4 avA[8], avB[8];
            #pragma unroll
            for (int q = 0; q < 8; ++q)
                avA[q] = A4s[p * 256 + q];
#define TOK(I, avC, aC, erC, avN, aN, erN)                                     \
    {                                                                          \
        if ((I) < 31) {                                                        \
            _Pragma("unroll")                                                  \
            for (int q = 0; q < 8; ++q)                                        \
                avN[q] = A4s[p * 256 + ((I) + 1) * 8 + q];                     \
            aN  = ag[((I) + 1) * HD + lane];                                   \
            erN = eg[(I) + 1];                                                 \
        }                                                                      \
        float z  = Z[I];                                                       \
        float a  = aC;                                                         \
        float zg = z * w3;                                                     \
        float x1 = z, x2 = z * z, x3 = zg, x4 = zg * z, x5 = z * a;            \
        red5_asm(x1, x2, x3, x4, x5);                                          \
        float r1 = rl(x1, 63), r2 = rl(x2, 63), r3 = rl(x3, 63);               \
        float r4 = rl(x4, 63), r5 = rl(x5, 63);                                \
        float r6t = (erC).y;                                                   \
        float mu   = r1 * (1.f / 64.f);                                        \
        float var  = fmaf(-mu, mu, r2 * (1.f / 64.f));                         \
        float rstd = fast_rsq(var + EPSLN);                                    \
        float mc   = mu * Cg2;                                                 \
        float sgxh = fmaf(rstd, r3 - mc, r6t);                                 \
        float t4v  = fmaf(mu, mc, fmaf(-2.f * mu, r3, r4));                    \
        float sgz  = fmaf(rstd * rstd, t4v, rstd * (r5 - mu * r6t));           \
        float zh   = (z - mu) * rstd;                                          \
        float gxh  = fmaf(zh, w3, a);                                          \
        float ge   = (fmaf(64.f, gxh, -sgxh) - zh * sgz) * (rstd * (erC).x);   \
        Gl[I][lane] = ge;                                                      \
        _Pragma("unroll")                                                      \
        for (int u = (I) + 1; u < 32; ++u) {                                   \
            const float4 c4 = avC[(u) >> 2]; const int m4 = (u) & 3;           \
            float Atu = (m4 == 0) ? c4.x : (m4 == 1) ? c4.y                    \
                      : (m4 == 2) ? c4.z : c4.w;                               \
            Z[u] = fmaf(-Atu, ge, Z[u]);                                       \
        }                                                                      \
    }
            #pragma unroll
            for (int tp = 0; tp < 16; ++tp) {
                TOK(2 * tp,     avA, aA, erA, avB, aB, erB)
                TOK(2 * tp + 1, avB, aB, erB, avA, aA, erA)
            }
#undef TOK
        } else if (c < NCHUNK - 1) {
            stage_chunk(p ^ 1, c + 1, bh, tid - 64, 192, kbuf, Ab, K4s, A4s);
        }
        __syncthreads();   // (B) Gl ready; staging done

        // ---- P3 (all waves): W -= K^T@G ; b -= colsum(G); Gbuf -----------
        float btot = 0.f;
        #pragma unroll
        for (int s = 0; s < 32; ++s) {
            float gd = Gl[s][lane];
            btot += gd;
            #pragma unroll
            for (int r4 = 0; r4 < 4; ++r4) {
                const float4 kv = K4s[p * 512 + s * 16 + wv * 4 + r4];
                Wreg[r4 * 4 + 0] = fmaf(-kv.x, gd, Wreg[r4 * 4 + 0]);
                Wreg[r4 * 4 + 1] = fmaf(-kv.y, gd, Wreg[r4 * 4 + 1]);
                Wreg[r4 * 4 + 2] = fmaf(-kv.z, gd, Wreg[r4 * 4 + 2]);
                Wreg[r4 * 4 + 3] = fmaf(-kv.w, gd, Wreg[r4 * 4 + 3]);
            }
        }
        breg -= btot;
        {
            float* gb = Gbuf + ((size_t)bh * SDIM + cs) * HD + lane;
            #pragma unroll
            for (int r = 0; r < 8; ++r)
                gb[(wv * 8 + r) * HD] = Gl[wv * 8 + r][lane];
        }
    }
}

// ---------------- post: Zq = Qc@W0 + b0 - tril(B)@G ; ys = q + ln(Zq) ------
__global__ __launch_bounds__(256) void post_kernel(
    const float* __restrict__ qbuf, const float* __restrict__ Bb,
    const float* __restrict__ Gbuf, const float* __restrict__ W0save,
    const float* __restrict__ b0save,
    const float* __restrict__ ttt_g, const float* __restrict__ ttt_b,
    float* __restrict__ ys)
{
    const int bh = blockIdx.x >> 5, c = blockIdx.x & 31, cs = c * 32;
    const int b = bh / HDIM, hh = bh % HDIM;
    const int tid = threadIdx.x, lane = tid & 63, wave = tid >> 6;
    __shared__ float Qc[32][65];
    __shared__ float W0l[64][65];
    __shared__ float Gl[32][64];
    for (int i = tid; i < 2048; i += 256) {
        int t = i >> 6, j = i & 63;
        Qc[t][j] = qbuf[((size_t)bh * SDIM + cs + t) * HD + j];
        Gl[t][j] = Gbuf[((size_t)bh * SDIM + cs + t) * HD + j];
    }
    for (int i = tid; i < 4096; i += 256)
        W0l[i >> 6][i & 63] = W0save[((size_t)(bh * NCHUNK + c)) * 4096 + i];
    __syncthreads();

    const float bb0 = b0save[(bh * NCHUNK + c) * 64 + lane];
    const float gw = ttt_g[hh * 64 + lane], bw = ttt_b[hh * 64 + lane];
    float acc[8];
    #pragma unroll
    for (int r = 0; r < 8; ++r) acc[r] = bb0;
    for (int j = 0; j < 64; ++j) {
        float w0 = W0l[j][lane];
        #pragma unroll
        for (int r = 0; r < 8; ++r)
            acc[r] = fmaf(Qc[wave * 8 + r][j], w0, acc[r]);
    }
    float Breg[8];
    size_t bbase = ((size_t)(bh * NCHUNK + c)) * 1024;
    #pragma unroll
    for (int r = 0; r < 8; ++r)
        Breg[r] = Bb[bbase + (wave * 8 + r) * 32 + (lane & 31)];
    #pragma unroll
    for (int s = 0; s < 32; ++s) {
        float gd = Gl[s][lane];
        #pragma unroll
        for (int r = 0; r < 8; ++r) {
            int t = wave * 8 + r;
            float Bts = rl(Breg[r], s);
            acc[r] = (s <= t) ? fmaf(-Bts, gd, acc[r]) : acc[r];
        }
    }
    #pragma unroll
    for (int r = 0; r < 8; ++r) {
        int t = wave * 8 + r;
        float s1 = wave_bcast_sum(acc[r]);
        float s2 = wave_bcast_sum(acc[r] * acc[r]);
        float mu = s1 * (1.f / 64.f);
        float var = s2 * (1.f / 64.f) - mu * mu;
        float rstd = rsqrtf(var + EPSLN);
        float zh = (acc[r] - mu) * rstd;
        float val = zh * gw + bw + Qc[t][lane];
        ys[((size_t)(b * SDIM) + cs + t) * ADIM + hh * HD + lane] = val;
    }
}

// ---------------- launch ---------------------------------------------------
extern "C" void kernel_launch(void* const* d_in, const int* in_sizes, int n_in,
                              void* d_out, int out_size, void* d_ws, size_t ws_size,
                              hipStream_t stream)
{
    const float* x      = (const float*)d_in[0];
    const float* W_down = (const float*)d_in[1];
    const float* b_down = (const float*)d_in[2];
    const float* Wq     = (const float*)d_in[3];
    const float* Wk     = (const float*)d_in[4];
    const float* Wv     = (const float*)d_in[5];
    const float* Wo     = (const float*)d_in[6];
    const float* W1     = (const float*)d_in[7];
    const float* b1     = (const float*)d_in[8];
    const float* ttt_g  = (const float*)d_in[9];
    const float* ttt_b  = (const float*)d_in[10];
    const float* lr_w   = (const float*)d_in[11];
    const float* lr_b   = (const float*)d_in[12];
    const float* post_g = (const float*)d_in[13];
    const float* post_b = (const float*)d_in[14];
    const float* norm_g = (const float*)d_in[15];
    const float* norm_b = (const float*)d_in[16];
    const float* W_up   = (const float*)d_in[17];
    const float* b_up   = (const float*)d_in[18];
    float* out = (float*)d_out;

    float* ws = (float*)d_ws;
    const size_t SZ = (size_t)MROWS * ADIM;      // 786432
    float* h    = ws;                // [4096][192]
    float* qb   = ws + SZ;           // [12][1024][64]
    float* kb   = ws + 2 * SZ;
    float* vb   = ws + 3 * SZ;       // after ab_kernel: a-vectors
    float* Gb   = ws + 4 * SZ;
    float2* er6b = (float2*)(ws + 5 * SZ);           // 12288 float2 (eta, r6)
    float* Ab   = ws + 5 * SZ + 24576;               // 393216
    float* Bb   = Ab + 393216;                       // 393216
    float* W0s  = Bb + 393216;                       // 1572864
    float* b0s  = W0s + 1572864;                     // 24576
    float2* lnst = (float2*)(b0s + 24576);           // 4096 float2
    // aliases (lifetime-disjoint)
    float* ysb  = h;    // post_kernel output (h dead after eta)
    float* tbuf = qb;   // ln(ys)@Wo (qb dead after post_kernel)

    // 1) h = silu(x @ W_down + b_down)
    gemm_k<1, 0, 0><<<dim3(ADIM / 64, MROWS / 64), 256, 0, stream>>>(
        x, W_down, b_down, h, MROWS, ADIM, DDIM, nullptr, nullptr, nullptr);
    // 2) q,k,v in ONE launch
    gemm_qkv<<<dim3(ADIM / 64, MROWS / 64, 3), 256, 0, stream>>>(
        h, Wq, Wk, Wv, qb);
    // 3) eta (per-row coalesced) -> er6b.x
    eta_kernel<<<MROWS, 192, 0, stream>>>(h, lr_w, lr_b, er6b);
    // 4) chunk coefficient matrices + a-vectors (in vb) + r6 -> er6b.y
    ab_kernel<<<BDIM * HDIM * NCHUNK, 256, 0, stream>>>(
        qb, kb, vb, ttt_g, ttt_b, Ab, Bb, er6b);
    // 5) sequential scan (merged 32-token serial pass, 56 KB LDS)
    ttt_scan<<<BDIM * HDIM, 256, 0, stream>>>(
        kb, vb, er6b, Ab, W1, b1, ttt_g, ttt_b, Gb, W0s, b0s);
    // 6) outputs ys = q + ln(Zq)
    post_kernel<<<BDIM * HDIM * NCHUNK, 256, 0, stream>>>(
        qb, Bb, Gb, W0s, b0s, ttt_g, ttt_b, ysb);
    // 7) t = ln(ys) @ Wo   (LN fused into GEMM A-load)
    lnstats<<<MROWS, 64, 0, stream>>>(ysb, lnst);
    gemm_k<0, 0, 1><<<dim3(ADIM / 64, MROWS / 64), 256, 0, stream>>>(
        ysb, Wo, nullptr, tbuf, MROWS, ADIM, ADIM, lnst, post_g, post_b);
    // 8) out = ln(t) @ W_up + b_up   (LN fused into GEMM A-load)
    lnstats<<<MROWS, 64, 0, stream>>>(tbuf, lnst);
    gemm_k<0, 0, 1><<<dim3(DDIM / 64, MROWS / 64), 256, 0, stream>>>(
        tbuf, W_up, b_up, out, MROWS, DDIM, ADIM, lnst, norm_g, norm_b);
}

// Round 4
// 571.509 us; speedup vs baseline: 1.0713x; 1.0162x over previous
//
#include <hip/hip_runtime.h>
#include <hip/hip_bf16.h>
#include <math.h>

// Problem shape (fixed): B=4, S=1024, D=768, A=192, H=3, hd=64
#define BDIM 4
#define SDIM 1024
#define DDIM 768
#define ADIM 192
#define HDIM 3
#define HD   64
#define MROWS (BDIM*SDIM)      // 4096
#define NCHUNK (SDIM/32)       // 32
#define EPSLN 1e-6f

// ---------------- DPP wave reduction (64-lane sum, result broadcast) -------
template<int CTRL, int RMASK, bool BC>
__device__ __forceinline__ float dpp_add_step(float x) {
    int t = __builtin_amdgcn_update_dpp(0, __float_as_int(x), CTRL, RMASK, 0xf, BC);
    return x + __int_as_float(t);
}
__device__ __forceinline__ float wave_bcast_sum(float x) {
    x = dpp_add_step<0x111, 0xf, true >(x);
    x = dpp_add_step<0x112, 0xf, true >(x);
    x = dpp_add_step<0x114, 0xf, true >(x);
    x = dpp_add_step<0x118, 0xf, true >(x);
    x = dpp_add_step<0x142, 0xa, false>(x);
    x = dpp_add_step<0x143, 0xc, false>(x);
    return __int_as_float(__builtin_amdgcn_readlane(__float_as_int(x), 63));
}
__device__ __forceinline__ float rl(float v, int lane) {
    return __int_as_float(__builtin_amdgcn_readlane(__float_as_int(v), lane));
}
__device__ __forceinline__ float fast_rsq(float x) {
    float r;
    asm("v_rsq_f32 %0, %1" : "=v"(r) : "v"(x));
    return r;
}
// 5 simultaneous 64-lane sums via fused DPP adds (validated r7-r10).
__device__ __forceinline__ void red5_asm(float& a, float& b, float& c,
                                         float& d, float& e) {
#define R5_SHR(N)                                                              \
    asm("v_add_f32 %0, %0, %0 row_shr:" #N " row_mask:0xf bank_mask:0xf bound_ctrl:0" : "+v"(a)); \
    asm("v_add_f32 %0, %0, %0 row_shr:" #N " row_mask:0xf bank_mask:0xf bound_ctrl:0" : "+v"(b)); \
    asm("v_add_f32 %0, %0, %0 row_shr:" #N " row_mask:0xf bank_mask:0xf bound_ctrl:0" : "+v"(c)); \
    asm("v_add_f32 %0, %0, %0 row_shr:" #N " row_mask:0xf bank_mask:0xf bound_ctrl:0" : "+v"(d)); \
    asm("v_add_f32 %0, %0, %0 row_shr:" #N " row_mask:0xf bank_mask:0xf bound_ctrl:0" : "+v"(e));
#define R5_BC(N, RM)                                                           \
    asm("v_add_f32 %0, %0, %0 row_bcast:" #N " row_mask:" #RM " bank_mask:0xf" : "+v"(a)); \
    asm("v_add_f32 %0, %0, %0 row_bcast:" #N " row_mask:" #RM " bank_mask:0xf" : "+v"(b)); \
    asm("v_add_f32 %0, %0, %0 row_bcast:" #N " row_mask:" #RM " bank_mask:0xf" : "+v"(c)); \
    asm("v_add_f32 %0, %0, %0 row_bcast:" #N " row_mask:" #RM " bank_mask:0xf" : "+v"(d)); \
    asm("v_add_f32 %0, %0, %0 row_bcast:" #N " row_mask:" #RM " bank_mask:0xf" : "+v"(e));
    R5_SHR(1) R5_SHR(2) R5_SHR(4) R5_SHR(8)
    R5_BC(15, 0xa) R5_BC(31, 0xc)
#undef R5_SHR
#undef R5_BC
}

// ---------------- per-row LayerNorm stats: (mu, rstd) over 192 -------------
__global__ __launch_bounds__(64) void lnstats(
    const float* __restrict__ in, float2* __restrict__ st)
{
    int row = blockIdx.x, tid = threadIdx.x;
    float x0 = in[(size_t)row * ADIM + tid];
    float x1 = in[(size_t)row * ADIM + 64 + tid];
    float x2 = in[(size_t)row * ADIM + 128 + tid];
    float s1 = wave_bcast_sum((x0 + x1) + x2);
    float s2 = wave_bcast_sum(fmaf(x0, x0, fmaf(x1, x1, x2 * x2)));
    if (tid == 0) {
        float mu = s1 * (1.f / 192.f);
        float var = s2 * (1.f / 192.f) - mu * mu;
        st[row] = make_float2(mu, rsqrtf(var + EPSLN));
    }
}

// ---------------- Generic fp32 tiled GEMM: C = act(lnA(A)@B + bias) --------
template<int ACT, int LAYOUT, int LNA>
__global__ __launch_bounds__(256) void gemm_k(
    const float* __restrict__ A, const float* __restrict__ Bm,
    const float* __restrict__ bias, float* __restrict__ C,
    int M, int N, int K,
    const float2* __restrict__ lnst, const float* __restrict__ lng,
    const float* __restrict__ lnbb)
{
    __shared__ float As[16][68];
    __shared__ float Bs[16][68];
    const int tid = threadIdx.x;
    const int bm = blockIdx.y * 64, bn = blockIdx.x * 64;
    const int tr = tid >> 4, tc = tid & 15;
    float acc[4][4] = {};

    for (int k0 = 0; k0 < K; k0 += 16) {
        #pragma unroll
        for (int p = 0; p < 4; ++p) {
            int m = (tid >> 4) + p * 16;
            int kk = tid & 15;
            float av = A[(size_t)(bm + m) * K + k0 + kk];
            if (LNA) {
                float2 stv = lnst[bm + m];
                av = fmaf((av - stv.x) * stv.y, lng[k0 + kk], lnbb[k0 + kk]);
            }
            As[kk][m] = av;
        }
        #pragma unroll
        for (int p = 0; p < 4; ++p) {
            int kk = (tid >> 6) + p * 4;
            int n = tid & 63;
            Bs[kk][n] = Bm[(size_t)(k0 + kk) * N + bn + n];
        }
        __syncthreads();
        #pragma unroll
        for (int kk = 0; kk < 16; ++kk) {
            // 16B-aligned: As row stride 272B, offsets are multiples of 16B
            const float4 a4 = *(const float4*)&As[kk][tr * 4];
            const float4 b4 = *(const float4*)&Bs[kk][tc * 4];
            float aa[4] = {a4.x, a4.y, a4.z, a4.w};
            float bb[4] = {b4.x, b4.y, b4.z, b4.w};
            #pragma unroll
            for (int i = 0; i < 4; ++i)
                #pragma unroll
                for (int j = 0; j < 4; ++j)
                    acc[i][j] = fmaf(aa[i], bb[j], acc[i][j]);
        }
        __syncthreads();
    }

    #pragma unroll
    for (int i = 0; i < 4; ++i) {
        int m = bm + tr * 4 + i;
        #pragma unroll
        for (int j = 0; j < 4; ++j) {
            int n = bn + tc * 4 + j;
            float v = acc[i][j];
            if (bias) v += bias[n];
            if (ACT == 1) v = v / (1.f + __expf(-v));   // silu
            if (LAYOUT == 0) {
                C[(size_t)m * N + n] = v;
            } else {
                int b  = m >> 10, s = m & 1023;
                int hh = n >> 6,  d = n & 63;
                C[(((size_t)b * HDIM + hh) * SDIM + s) * HD + d] = v;
            }
        }
    }
}

// ---------------- fused QKV GEMM: one launch, blockIdx.z picks the head ----
__global__ __launch_bounds__(256) void gemm_qkv(
    const float* __restrict__ A, const float* __restrict__ BWq,
    const float* __restrict__ BWk, const float* __restrict__ BWv,
    float* __restrict__ Cbase)
{
    const float* Bm = (blockIdx.z == 0) ? BWq : (blockIdx.z == 1) ? BWk : BWv;
    float* C = Cbase + (size_t)blockIdx.z * ((size_t)MROWS * ADIM);
    __shared__ float As[16][68];
    __shared__ float Bs[16][68];
    const int tid = threadIdx.x;
    const int bm = blockIdx.y * 64, bn = blockIdx.x * 64;
    const int tr = tid >> 4, tc = tid & 15;
    float acc[4][4] = {};

    for (int k0 = 0; k0 < ADIM; k0 += 16) {
        #pragma unroll
        for (int p = 0; p < 4; ++p) {
            int m = (tid >> 4) + p * 16;
            int kk = tid & 15;
            As[kk][m] = A[(size_t)(bm + m) * ADIM + k0 + kk];
        }
        #pragma unroll
        for (int p = 0; p < 4; ++p) {
            int kk = (tid >> 6) + p * 4;
            int n = tid & 63;
            Bs[kk][n] = Bm[(size_t)(k0 + kk) * ADIM + bn + n];
        }
        __syncthreads();
        #pragma unroll
        for (int kk = 0; kk < 16; ++kk) {
            const float4 a4 = *(const float4*)&As[kk][tr * 4];
            const float4 b4 = *(const float4*)&Bs[kk][tc * 4];
            float aa[4] = {a4.x, a4.y, a4.z, a4.w};
            float bb[4] = {b4.x, b4.y, b4.z, b4.w};
            #pragma unroll
            for (int i = 0; i < 4; ++i)
                #pragma unroll
                for (int j = 0; j < 4; ++j)
                    acc[i][j] = fmaf(aa[i], bb[j], acc[i][j]);
        }
        __syncthreads();
    }

    #pragma unroll
    for (int i = 0; i < 4; ++i) {
        int m = bm + tr * 4 + i;
        #pragma unroll
        for (int j = 0; j < 4; ++j) {
            int n = bn + tc * 4 + j;
            int b  = m >> 10, s = m & 1023;
            int hh = n >> 6,  d = n & 63;
            C[(((size_t)b * HDIM + hh) * SDIM + s) * HD + d] = acc[i][j];
        }
    }
}

// ------- eta = sigmoid(h @ lr_w + lr_b)/(64*64) -> er6b[.].x ---------------
// (folds the staging-time extra 1/64 that ttt_scan's TOK formula expects)
__global__ __launch_bounds__(192) void eta_kernel(
    const float* __restrict__ h, const float* __restrict__ lr_w,
    const float* __restrict__ lr_b, float2* __restrict__ er6b)
{
    const int row = blockIdx.x, tid = threadIdx.x, wave = tid >> 6;
    __shared__ float part[3][3];   // [wave][hh]
    float hv = h[(size_t)row * ADIM + tid];
    float p0 = hv * lr_w[tid * 3 + 0];
    float p1 = hv * lr_w[tid * 3 + 1];
    float p2 = hv * lr_w[tid * 3 + 2];
    float s0 = wave_bcast_sum(p0);
    float s1 = wave_bcast_sum(p1);
    float s2 = wave_bcast_sum(p2);
    if ((tid & 63) == 0) {
        part[wave][0] = s0; part[wave][1] = s1; part[wave][2] = s2;
    }
    __syncthreads();
    if (tid < 3) {
        float acc = (part[0][tid] + part[1][tid]) + part[2][tid] + lr_b[tid];
        float e = 1.f / (1.f + __expf(-acc)) * (1.f / 4096.f);
        int b = row >> 10, s = row & 1023;
        er6b[(size_t)(b * HDIM + tid) * SDIM + s].x = e;
    }
}

// -- pre: A=[k.k+1], B=[q.k+1], a-vectors (into vb), r6 -> er6b[.].y ---------
__global__ __launch_bounds__(256) void ab_kernel(
    const float* __restrict__ qb, const float* __restrict__ kb,
    float* __restrict__ vb,            // in: v; out: a = (bw-(v-k))*gw
    const float* __restrict__ ttt_g, const float* __restrict__ ttt_b,
    float* __restrict__ Ab, float* __restrict__ Bb,
    float2* __restrict__ er6b)
{
    int bh = blockIdx.x >> 5, c = blockIdx.x & 31, cs = c * 32;
    int hh = bh % HDIM;
    __shared__ float Kc[32][65], Qc[32][65], Vc[32][65];
    for (int i = threadIdx.x; i < 2048; i += 256) {
        int t = i >> 6, j = i & 63;
        Kc[t][j] = kb[((size_t)bh * SDIM + cs + t) * HD + j];
        Qc[t][j] = qb[((size_t)bh * SDIM + cs + t) * HD + j];
        Vc[t][j] = vb[((size_t)bh * SDIM + cs + t) * HD + j];
    }
    __syncthreads();
    size_t base = ((size_t)(bh * NCHUNK + c)) * 1024;
    for (int e = threadIdx.x; e < 1024; e += 256) {
        int t = e >> 5, s = e & 31;
        float a = 1.f, b = 1.f;
        #pragma unroll
        for (int j = 0; j < 64; ++j) {
            float ks = Kc[s][j];
            a = fmaf(Kc[t][j], ks, a);
            b = fmaf(Qc[t][j], ks, b);
        }
        Ab[base + e] = a;
        Bb[base + e] = b;
    }
    for (int i = threadIdx.x; i < 2048; i += 256) {
        int t = i >> 6, j = i & 63;
        float gwv = ttt_g[hh * 64 + j], bwv = ttt_b[hh * 64 + j];
        float av = fmaf(-(Vc[t][j] - Kc[t][j]), gwv, bwv * gwv);
        Vc[t][j] = av;
        vb[((size_t)bh * SDIM + cs + t) * HD + j] = av;
    }
    __syncthreads();
    if (threadIdx.x < 32) {
        int t = threadIdx.x;
        float acc = 0.f;
        #pragma unroll
        for (int j = 0; j < 64; ++j) acc += Vc[t][j];
        er6b[(size_t)bh * SDIM + cs + t].y = acc;
    }
}

// ---------------- staging helper (global -> LDS, float4): K and A only -----
__device__ __forceinline__ void stage_chunk(
    int pp, int cc, int bh, int idx, int nth,
    const float* __restrict__ kbuf, const float* __restrict__ Ab,
    float4* K4, float4* A4)
{
    const float4* kg = (const float4*)(kbuf + ((size_t)bh * SDIM + cc * 32) * HD);
    const float4* Ag = (const float4*)(Ab + ((size_t)(bh * NCHUNK + cc)) * 1024);
    for (int i = idx; i < 512; i += nth) K4[pp * 512 + i] = kg[i];
    for (int i = idx; i < 256; i += nth) A4[pp * 256 + i] = Ag[i];
}

// ---------------- the sequential TTT scan (12 blocks) ----------------------
// r14 = r13 (merged 32-token serial pass, hardware-validated math) with the
// diagnosed global-latency stall fixed:
//  - a / (eta,r6) global reads now prefetched 4 TOKENS ahead via a 4-slot
//    register rotation (slots for tokens 0-3 issued before P1's ~2k cy of
//    compute, so HBM latency ~900cy is always covered).
//  - A-row prefetch trimmed to needed columns (q >= (I+2)>>2, compile-time).
//  - breg folded into wave 1's P1 partial (saves 32 adds on wave 0).
//  - s_setprio(1) around wave 0's serial pass (waves have role-split here).
__global__ __launch_bounds__(256, 1) void ttt_scan(
    const float* __restrict__ kbuf, const float* __restrict__ abuf,
    const float2* __restrict__ er6b, const float* __restrict__ Ab,
    const float* __restrict__ W1,   const float* __restrict__ b1,
    const float* __restrict__ ttt_g, const float* __restrict__ ttt_b,
    float* __restrict__ Gbuf, float* __restrict__ W0save, float* __restrict__ b0save)
{
    const int bh = blockIdx.x, hh = bh % HDIM;
    const int tid = threadIdx.x, lane = tid & 63;
    const int wv = tid >> 6;
    __shared__ float  Zp[3][32][64];   // 24 KB: waves 1-3 Z0 partials
    __shared__ float4 K4s[2 * 512];    // 16 KB: K double-buffered
    __shared__ float4 A4s[2 * 256];    //  8 KB: A double-buffered
    __shared__ float  Gl[32][64];      //  8 KB: per-token eta*g (full chunk)

    float Wreg[16];
    #pragma unroll
    for (int r = 0; r < 16; ++r)
        Wreg[r] = W1[hh * 4096 + (wv * 16 + r) * 64 + lane];
    float breg = b1[hh * 64 + lane];
    const float gw = ttt_g[hh * 64 + lane];
    const float bw = ttt_b[hh * 64 + lane];
    const float w3 = gw * gw;
    (void)bw;
    const float Cg2 = wave_bcast_sum(w3);

    stage_chunk(0, 0, bh, tid, 256, kbuf, Ab, K4s, A4s);
    __syncthreads();

    for (int c = 0; c < NCHUNK; ++c) {
        const int cs = c * 32;
        const int p = c & 1;
        const float*  ag = abuf + ((size_t)bh * SDIM + cs) * HD;
        const float2* eg = er6b + (size_t)bh * SDIM + cs;

        {
            float* Wd = W0save + ((size_t)(bh * NCHUNK + c)) * 4096
                        + (wv * 16) * 64 + lane;
            #pragma unroll
            for (int r = 0; r < 16; ++r) Wd[r * 64] = Wreg[r];
            if (tid < 64) b0save[(bh * NCHUNK + c) * 64 + tid] = breg;
        }

        // ---- wave 0: issue 4-token-deep a/er prefetch before P1 ----------
        float a0, a1, a2, a3;
        float2 e0, e1, e2, e3;
        if (wv == 0) {
            a0 = ag[lane];          e0 = eg[0];
            a1 = ag[HD + lane];     e1 = eg[1];
            a2 = ag[2 * HD + lane]; e2 = eg[2];
            a3 = ag[3 * HD + lane]; e3 = eg[3];
        }

        // ---- P1 (all waves): Z0 partials for all 32 tokens ---------------
        float Z[32];
        #pragma unroll
        for (int i = 0; i < 32; ++i) {
            float zt = 0.f;
            #pragma unroll
            for (int r4 = 0; r4 < 4; ++r4) {
                const float4 kv = K4s[p * 512 + i * 16 + wv * 4 + r4];
                zt = fmaf(kv.x, Wreg[r4 * 4 + 0], zt);
                zt = fmaf(kv.y, Wreg[r4 * 4 + 1], zt);
                zt = fmaf(kv.z, Wreg[r4 * 4 + 2], zt);
                zt = fmaf(kv.w, Wreg[r4 * 4 + 3], zt);
            }
            if (wv != 0) Zp[wv - 1][i][lane] = (wv == 1) ? zt + breg : zt;
            else         Z[i] = zt;
        }
        __syncthreads();   // (A) Zp ready; buffer p staged

        // ---- P2: wave 0 serial over 32 tokens; waves 1-3 stage next ------
        if (wv == 0) {
            __builtin_amdgcn_s_setprio(1);
            #pragma unroll
            for (int i = 0; i < 32; ++i)
                Z[i] = ((Z[i] + Zp[0][i][lane]) +
                        (Zp[1][i][lane] + Zp[2][i][lane]));
            float4 avA[8], avB[8];
            #pragma unroll
            for (int q = 0; q < 8; ++q)
                avA[q] = A4s[p * 256 + q];
#define TOK(I, aS, erS, avC, avN)                                              \
    {                                                                          \
        float a  = aS;                                                         \
        float2 er = erS;                                                       \
        if ((I) < 28) {                                                        \
            aS  = ag[((I) + 4) * HD + lane];                                   \
            erS = eg[(I) + 4];                                                 \
        }                                                                      \
        if ((I) < 31) {                                                        \
            _Pragma("unroll")                                                  \
            for (int q = ((I) + 2) >> 2; q < 8; ++q)                           \
                avN[q] = A4s[p * 256 + ((I) + 1) * 8 + q];                     \
        }                                                                      \
        float z  = Z[I];                                                       \
        float zg = z * w3;                                                     \
        float x1 = z, x2 = z * z, x3 = zg, x4 = zg * z, x5 = z * a;            \
        red5_asm(x1, x2, x3, x4, x5);                                          \
        float r1 = rl(x1, 63), r2 = rl(x2, 63), r3 = rl(x3, 63);               \
        float r4 = rl(x4, 63), r5 = rl(x5, 63);                                \
        float r6t = er.y;                                                      \
        float mu   = r1 * (1.f / 64.f);                                        \
        float var  = fmaf(-mu, mu, r2 * (1.f / 64.f));                         \
        float rstd = fast_rsq(var + EPSLN);                                    \
        float mc   = mu * Cg2;                                                 \
        float sgxh = fmaf(rstd, r3 - mc, r6t);                                 \
        float t4v  = fmaf(mu, mc, fmaf(-2.f * mu, r3, r4));                    \
        float sgz  = fmaf(rstd * rstd, t4v, rstd * (r5 - mu * r6t));           \
        float zh   = (z - mu) * rstd;                                          \
        float gxh  = fmaf(zh, w3, a);                                          \
        float ge   = (fmaf(64.f, gxh, -sgxh) - zh * sgz) * (rstd * er.x);      \
        Gl[I][lane] = ge;                                                      \
        _Pragma("unroll")                                                      \
        for (int u = (I) + 1; u < 32; ++u) {                                   \
            const float4 c4 = avC[(u) >> 2]; const int m4 = (u) & 3;           \
            float Atu = (m4 == 0) ? c4.x : (m4 == 1) ? c4.y                    \
                      : (m4 == 2) ? c4.z : c4.w;                               \
            Z[u] = fmaf(-Atu, ge, Z[u]);                                       \
        }                                                                      \
    }
            #pragma unroll
            for (int tp = 0; tp < 8; ++tp) {
                TOK(4 * tp + 0, a0, e0, avA, avB)
                TOK(4 * tp + 1, a1, e1, avB, avA)
                TOK(4 * tp + 2, a2, e2, avA, avB)
                TOK(4 * tp + 3, a3, e3, avB, avA)
            }
#undef TOK
            __builtin_amdgcn_s_setprio(0);
        } else if (c < NCHUNK - 1) {
            stage_chunk(p ^ 1, c + 1, bh, tid - 64, 192, kbuf, Ab, K4s, A4s);
        }
        __syncthreads();   // (B) Gl ready; staging done

        // ---- P3 (all waves): W -= K^T@G ; b -= colsum(G); Gbuf -----------
        float btot = 0.f;
        #pragma unroll
        for (int s = 0; s < 32; ++s) {
            float gd = Gl[s][lane];
            btot += gd;
            #pragma unroll
            for (int r4 = 0; r4 < 4; ++r4) {
                const float4 kv = K4s[p * 512 + s * 16 + wv * 4 + r4];
                Wreg[r4 * 4 + 0] = fmaf(-kv.x, gd, Wreg[r4 * 4 + 0]);
                Wreg[r4 * 4 + 1] = fmaf(-kv.y, gd, Wreg[r4 * 4 + 1]);
                Wreg[r4 * 4 + 2] = fmaf(-kv.z, gd, Wreg[r4 * 4 + 2]);
                Wreg[r4 * 4 + 3] = fmaf(-kv.w, gd, Wreg[r4 * 4 + 3]);
            }
        }
        breg -= btot;
        {
            float* gb = Gbuf + ((size_t)bh * SDIM + cs) * HD + lane;
            #pragma unroll
            for (int r = 0; r < 8; ++r)
                gb[(wv * 8 + r) * HD] = Gl[wv * 8 + r][lane];
        }
    }
}

// ---------------- post: Zq = Qc@W0 + b0 - tril(B)@G ; ys = q + ln(Zq) ------
__global__ __launch_bounds__(256) void post_kernel(
    const float* __restrict__ qbuf, const float* __restrict__ Bb,
    const float* __restrict__ Gbuf, const float* __restrict__ W0save,
    const float* __restrict__ b0save,
    const float* __restrict__ ttt_g, const float* __restrict__ ttt_b,
    float* __restrict__ ys)
{
    const int bh = blockIdx.x >> 5, c = blockIdx.x & 31, cs = c * 32;
    const int b = bh / HDIM, hh = bh % HDIM;
    const int tid = threadIdx.x, lane = tid & 63, wave = tid >> 6;
    __shared__ float Qc[32][65];
    __shared__ float W0l[64][65];
    __shared__ float Gl[32][64];
    for (int i = tid; i < 2048; i += 256) {
        int t = i >> 6, j = i & 63;
        Qc[t][j] = qbuf[((size_t)bh * SDIM + cs + t) * HD + j];
        Gl[t][j] = Gbuf[((size_t)bh * SDIM + cs + t) * HD + j];
    }
    for (int i = tid; i < 4096; i += 256)
        W0l[i >> 6][i & 63] = W0save[((size_t)(bh * NCHUNK + c)) * 4096 + i];
    __syncthreads();

    const float bb0 = b0save[(bh * NCHUNK + c) * 64 + lane];
    const float gw = ttt_g[hh * 64 + lane], bw = ttt_b[hh * 64 + lane];
    float acc[8];
    #pragma unroll
    for (int r = 0; r < 8; ++r) acc[r] = bb0;
    for (int j = 0; j < 64; ++j) {
        float w0 = W0l[j][lane];
        #pragma unroll
        for (int r = 0; r < 8; ++r)
            acc[r] = fmaf(Qc[wave * 8 + r][j], w0, acc[r]);
    }
    float Breg[8];
    size_t bbase = ((size_t)(bh * NCHUNK + c)) * 1024;
    #pragma unroll
    for (int r = 0; r < 8; ++r)
        Breg[r] = Bb[bbase + (wave * 8 + r) * 32 + (lane & 31)];
    #pragma unroll
    for (int s = 0; s < 32; ++s) {
        float gd = Gl[s][lane];
        #pragma unroll
        for (int r = 0; r < 8; ++r) {
            int t = wave * 8 + r;
            float Bts = rl(Breg[r], s);
            acc[r] = (s <= t) ? fmaf(-Bts, gd, acc[r]) : acc[r];
        }
    }
    #pragma unroll
    for (int r = 0; r < 8; ++r) {
        int t = wave * 8 + r;
        float s1 = wave_bcast_sum(acc[r]);
        float s2 = wave_bcast_sum(acc[r] * acc[r]);
        float mu = s1 * (1.f / 64.f);
        float var = s2 * (1.f / 64.f) - mu * mu;
        float rstd = rsqrtf(var + EPSLN);
        float zh = (acc[r] - mu) * rstd;
        float val = zh * gw + bw + Qc[t][lane];
        ys[((size_t)(b * SDIM) + cs + t) * ADIM + hh * HD + lane] = val;
    }
}

// ---------------- launch ---------------------------------------------------
extern "C" void kernel_launch(void* const* d_in, const int* in_sizes, int n_in,
                              void* d_out, int out_size, void* d_ws, size_t ws_size,
                              hipStream_t stream)
{
    const float* x      = (const float*)d_in[0];
    const float* W_down = (const float*)d_in[1];
    const float* b_down = (const float*)d_in[2];
    const float* Wq     = (const float*)d_in[3];
    const float* Wk     = (const float*)d_in[4];
    const float* Wv     = (const float*)d_in[5];
    const float* Wo     = (const float*)d_in[6];
    const float* W1     = (const float*)d_in[7];
    const float* b1     = (const float*)d_in[8];
    const float* ttt_g  = (const float*)d_in[9];
    const float* ttt_b  = (const float*)d_in[10];
    const float* lr_w   = (const float*)d_in[11];
    const float* lr_b   = (const float*)d_in[12];
    const float* post_g = (const float*)d_in[13];
    const float* post_b = (const float*)d_in[14];
    const float* norm_g = (const float*)d_in[15];
    const float* norm_b = (const float*)d_in[16];
    const float* W_up   = (const float*)d_in[17];
    const float* b_up   = (const float*)d_in[18];
    float* out = (float*)d_out;

    float* ws = (float*)d_ws;
    const size_t SZ = (size_t)MROWS * ADIM;      // 786432
    float* h    = ws;                // [4096][192]
    float* qb   = ws + SZ;           // [12][1024][64]
    float* kb   = ws + 2 * SZ;
    float* vb   = ws + 3 * SZ;       // after ab_kernel: a-vectors
    float* Gb   = ws + 4 * SZ;
    float2* er6b = (float2*)(ws + 5 * SZ);           // 12288 float2 (eta, r6)
    float* Ab   = ws + 5 * SZ + 24576;               // 393216
    float* Bb   = Ab + 393216;                       // 393216
    float* W0s  = Bb + 393216;                       // 1572864
    float* b0s  = W0s + 1572864;                     // 24576
    float2* lnst = (float2*)(b0s + 24576);           // 4096 float2
    // aliases (lifetime-disjoint)
    float* ysb  = h;    // post_kernel output (h dead after eta)
    float* tbuf = qb;   // ln(ys)@Wo (qb dead after post_kernel)

    // 1) h = silu(x @ W_down + b_down)
    gemm_k<1, 0, 0><<<dim3(ADIM / 64, MROWS / 64), 256, 0, stream>>>(
        x, W_down, b_down, h, MROWS, ADIM, DDIM, nullptr, nullptr, nullptr);
    // 2) q,k,v in ONE launch
    gemm_qkv<<<dim3(ADIM / 64, MROWS / 64, 3), 256, 0, stream>>>(
        h, Wq, Wk, Wv, qb);
    // 3) eta (per-row coalesced) -> er6b.x
    eta_kernel<<<MROWS, 192, 0, stream>>>(h, lr_w, lr_b, er6b);
    // 4) chunk coefficient matrices + a-vectors (in vb) + r6 -> er6b.y
    ab_kernel<<<BDIM * HDIM * NCHUNK, 256, 0, stream>>>(
        qb, kb, vb, ttt_g, ttt_b, Ab, Bb, er6b);
    // 5) sequential scan (merged 32-token serial pass, 4-deep prefetch)
    ttt_scan<<<BDIM * HDIM, 256, 0, stream>>>(
        kb, vb, er6b, Ab, W1, b1, ttt_g, ttt_b, Gb, W0s, b0s);
    // 6) outputs ys = q + ln(Zq)
    post_kernel<<<BDIM * HDIM * NCHUNK, 256, 0, stream>>>(
        qb, Bb, Gb, W0s, b0s, ttt_g, ttt_b, ysb);
    // 7) t = ln(ys) @ Wo   (LN fused into GEMM A-load)
    lnstats<<<MROWS, 64, 0, stream>>>(ysb, lnst);
    gemm_k<0, 0, 1><<<dim3(ADIM / 64, MROWS / 64), 256, 0, stream>>>(
        ysb, Wo, nullptr, tbuf, MROWS, ADIM, ADIM, lnst, post_g, post_b);
    // 8) out = ln(t) @ W_up + b_up   (LN fused into GEMM A-load)
    lnstats<<<MROWS, 64, 0, stream>>>(tbuf, lnst);
    gemm_k<0, 0, 1><<<dim3(DDIM / 64, MROWS / 64), 256, 0, stream>>>(
        tbuf, W_up, b_up, out, MROWS, DDIM, ADIM, lnst, norm_g, norm_b);
}